// Round 9
// baseline (228.876 us; speedup 1.0000x reference)
//
#include <hip/hip_runtime.h>

// MHA decode: B=256, NKEYS=2048, EMB=512, H=8, dh=64, f32.
// R8: fine-grained blocks for HW-dispatch load balancing. 2048 blocks
// (batch x 8 chunks of 256 keys) x 256 threads; each block ballot-compacts
// its chunk and streams K+V fused (R7 inner loop), writing RAW partials
// (8 denoms + 512 acc) to ws. Merge+proj kernel sums the 8 chunks, divides
// by the global per-head denominator, then projects (tiled W_o, L2-hot).
// Greedy HW block dispatch smooths the Binomial(2048,.5) per-batch key-count
// variance that made the 1-block-per-CU version end on a ~+6% straggler.

#define NB    256
#define NK    2048
#define EMBD  512
#define NH    8
#define DH    64
#define CHUNKS 8
#define CKEYS  256          // keys per chunk
#define PREC   520          // partial record: [8 denom][512 acc]
#define ACP    520

__device__ __forceinline__ void barrier_lgkm() {
    asm volatile("s_waitcnt lgkmcnt(0)" ::: "memory");
    __builtin_amdgcn_s_barrier();
}

__device__ __forceinline__ float4 ld4(const float* p) {
    return *reinterpret_cast<const float4*>(p);
}

// ---------------- R8 path: chunked attention ----------------
// 256 threads = 4 waves. Lane l owns floats [l*8, l*8+8) of each 2KB row
// (head h = l>>3). Waves pull rows from this chunk's compacted key list
// in stride-4 slots, fused K+V, 2-stage pipeline.
__global__ __launch_bounds__(256) void attn_chunk_kernel(
    const float* __restrict__ q,
    const float* __restrict__ kptr,
    const float* __restrict__ vptr,
    const int* __restrict__ mask,
    float* __restrict__ partials)
{
    const int bid  = blockIdx.x;
    const int b    = bid >> 3;
    const int c    = bid & 7;
    const int t    = threadIdx.x;
    const int w    = t >> 6;        // wave 0..3
    const int lane = t & 63;
    const int hq   = lane >> 3;
    const int sub  = lane & 7;

    __shared__ int   klist[CKEYS];
    __shared__ int   wavecnt[4];
    __shared__ float redl[4][NH];
    __shared__ float accb[4 * ACP];

    const float* qb = q + (size_t)b * EMBD + lane * 8;
    const float4 qa = ld4(qb);
    const float4 qc = ld4(qb + 4);
    const float* kb = kptr + (size_t)b * NK * EMBD + lane * 8;
    const float* vb = vptr + (size_t)b * NK * EMBD + lane * 8;
    const int*   mrow = mask + (size_t)b * NK + c * CKEYS;

    // ---- ballot-compact this chunk's unmasked keys ----
    const int myk = w * 64 + lane;             // 0..255 within chunk
    const int mk  = mrow[myk];
    const unsigned long long bal = __ballot(mk == 0);
    if (lane == 0) wavecnt[w] = __popcll(bal);
    __syncthreads();
    int off = 0, nun = 0;
    #pragma unroll
    for (int i = 0; i < 4; ++i) {
        const int cc = wavecnt[i];
        off += (i < w) ? cc : 0;
        nun += cc;
    }
    const unsigned long long below = (1ull << lane) - 1ull;
    if (!mk) klist[off + __popcll(bal & below)] = c * CKEYS + myk;
    __syncthreads();

    // ---- fused K+V stream over compacted keys, 2-stage pipeline ----
    float lsum = 0.f;
    float4 a0 = {0.f, 0.f, 0.f, 0.f};
    float4 a1 = {0.f, 0.f, 0.f, 0.f};
    {
        int key0 = (w < nun) ? klist[w] : -1;
        int key1 = (w + 4 < nun) ? klist[w + 4] : -1;
        float4 ka = {0,0,0,0}, kc = {0,0,0,0};
        float4 va = {0,0,0,0}, vc = {0,0,0,0};
        if (key0 >= 0) {
            const float* kk = kb + (size_t)key0 * EMBD;
            const float* vv = vb + (size_t)key0 * EMBD;
            ka = ld4(kk); kc = ld4(kk + 4);
            va = ld4(vv); vc = ld4(vv + 4);
        }
        for (int slot = w; slot < nun; slot += 4) {
            float4 nka = {0,0,0,0}, nkc = {0,0,0,0};
            float4 nva = {0,0,0,0}, nvc = {0,0,0,0};
            if (key1 >= 0) {
                const float* kk = kb + (size_t)key1 * EMBD;
                const float* vv = vb + (size_t)key1 * EMBD;
                nka = ld4(kk); nkc = ld4(kk + 4);
                nva = ld4(vv); nvc = ld4(vv + 4);
            }
            const int key2 = (slot + 8 < nun) ? klist[slot + 8] : -1;
            float sv = qa.x * ka.x + qa.y * ka.y + qa.z * ka.z + qa.w * ka.w
                     + qc.x * kc.x + qc.y * kc.y + qc.z * kc.z + qc.w * kc.w;
            sv += __shfl_xor(sv, 1, 8);
            sv += __shfl_xor(sv, 2, 8);
            sv += __shfl_xor(sv, 4, 8);
            const float p = __expf(sv * 0.125f);   // no max-subtraction needed
            lsum += p;
            a0.x = fmaf(p, va.x, a0.x); a0.y = fmaf(p, va.y, a0.y);
            a0.z = fmaf(p, va.z, a0.z); a0.w = fmaf(p, va.w, a0.w);
            a1.x = fmaf(p, vc.x, a1.x); a1.y = fmaf(p, vc.y, a1.y);
            a1.z = fmaf(p, vc.z, a1.z); a1.w = fmaf(p, vc.w, a1.w);
            key0 = key1; ka = nka; kc = nkc; va = nva; vc = nvc; key1 = key2;
        }
    }
    if (sub == 0) redl[w][hq] = lsum;
    *reinterpret_cast<float4*>(&accb[w * ACP + lane * 8])     = a0;
    *reinterpret_cast<float4*>(&accb[w * ACP + lane * 8 + 4]) = a1;
    __syncthreads();

    // ---- write raw partial record (denoms undivided) ----
    float* rec = partials + (size_t)bid * PREC;
    if (t < NH)
        rec[t] = redl[0][t] + redl[1][t] + redl[2][t] + redl[3][t];
    const float s0 = accb[t] + accb[ACP + t] + accb[2 * ACP + t] + accb[3 * ACP + t];
    const int t2 = t + 256;
    const float s1 = accb[t2] + accb[ACP + t2] + accb[2 * ACP + t2] + accb[3 * ACP + t2];
    rec[8 + t]  = s0;
    rec[8 + t2] = s1;
}

// Merge 8 chunk-partials per batch, divide by global denom, then project.
// Block = 8 batches x 64 j's (W_o tile stays L2-resident).
__global__ __launch_bounds__(256) void merge_proj_kernel(
    const float* __restrict__ partials,
    const float* __restrict__ Wo,
    float* __restrict__ out)
{
    const int bt = blockIdx.x >> 3;   // batch tile (8 batches)
    const int jt = blockIdx.x & 7;    // j tile (64 outputs)
    const int t  = threadIdx.x;
    __shared__ float mrow[8][EMBD];   // 16KB merged rows
    __shared__ float sden[64];

    if (t < 64) {
        const int bb = t >> 3, h = t & 7;
        const float* base = partials + (size_t)((bt * 8 + bb) * 8) * PREC;
        float d = 0.f;
        #pragma unroll
        for (int cc = 0; cc < 8; ++cc) d += base[cc * PREC + h];
        sden[t] = d;
    }
    #pragma unroll
    for (int e = 0; e < 16; ++e) {
        const int idx = e * 256 + t;
        const int bb = idx >> 9, el = idx & 511;
        const float* base = partials + (size_t)((bt * 8 + bb) * 8) * PREC + 8 + el;
        float s = 0.f;
        #pragma unroll
        for (int cc = 0; cc < 8; ++cc) s += base[cc * PREC];
        mrow[bb][el] = s;
    }
    __syncthreads();
    #pragma unroll
    for (int e = 0; e < 16; ++e) {
        const int idx = e * 256 + t;
        const int bb = idx >> 9, el = idx & 511;
        mrow[bb][el] /= sden[bb * 8 + (el >> 6)];
    }
    __syncthreads();

    const int j    = jt * 64 + (t & 63);
    const int brel = t >> 6;
    const float4* wrow = reinterpret_cast<const float4*>(Wo + (size_t)j * EMBD);
    const float4* m0 = reinterpret_cast<const float4*>(&mrow[brel][0]);
    const float4* m1 = reinterpret_cast<const float4*>(&mrow[brel + 4][0]);
    float s0 = 0.f, s1 = 0.f;
    #pragma unroll 4
    for (int i = 0; i < 128; ++i) {
        const float4 wv = wrow[i];
        const float4 x0 = m0[i];
        const float4 x1 = m1[i];
        s0 += wv.x * x0.x + wv.y * x0.y + wv.z * x0.z + wv.w * x0.w;
        s1 += wv.x * x1.x + wv.y * x1.y + wv.z * x1.z + wv.w * x1.w;
    }
    out[(size_t)(bt * 8 + brel) * EMBD + j] = s0;
    out[(size_t)(bt * 8 + brel + 4) * EMBD + j] = s1;
}

// ---------------- R7 fallback path (small ws) ----------------
__global__ __launch_bounds__(1024) void attn_kernel(
    const float* __restrict__ q,
    const float* __restrict__ kptr,
    const float* __restrict__ vptr,
    const int* __restrict__ mask,
    float* __restrict__ merged)
{
    const int b    = blockIdx.x;
    const int t    = threadIdx.x;
    const int w    = t >> 6;
    const int lane = t & 63;
    const int hq   = lane >> 3;
    const int sub  = lane & 7;

    __shared__ int   klist[NK];
    __shared__ int   wavecnt[16];
    __shared__ float redl[16][NH];
    __shared__ float accb[16 * ACP];

    const float* qb = q + (size_t)b * EMBD + lane * 8;
    const float4 qa = ld4(qb);
    const float4 qc = ld4(qb + 4);
    const float* kb = kptr + (size_t)b * NK * EMBD + lane * 8;
    const float* vb = vptr + (size_t)b * NK * EMBD + lane * 8;
    const int*   mrow = mask + (size_t)b * NK;

    const int kA = w * 128 + lane;
    const int kB = kA + 64;
    const int mA = mrow[kA];
    const int mB = mrow[kB];
    const unsigned long long balA = __ballot(mA == 0);
    const unsigned long long balB = __ballot(mB == 0);
    if (lane == 0) wavecnt[w] = __popcll(balA) + __popcll(balB);
    barrier_lgkm();

    int off = 0, nun = 0;
    #pragma unroll
    for (int i = 0; i < 16; ++i) {
        const int c = wavecnt[i];
        off += (i < w) ? c : 0;
        nun += c;
    }
    const unsigned long long below = (1ull << lane) - 1ull;
    if (!mA) klist[off + __popcll(balA & below)] = kA;
    if (!mB) klist[off + __popcll(balA) + __popcll(balB & below)] = kB;
    barrier_lgkm();

    float lsum = 0.f;
    float4 a0 = {0.f, 0.f, 0.f, 0.f};
    float4 a1 = {0.f, 0.f, 0.f, 0.f};
    {
        int key0 = (w < nun) ? klist[w] : -1;
        int key1 = (w + 16 < nun) ? klist[w + 16] : -1;
        float4 ka = {0,0,0,0}, kc = {0,0,0,0};
        float4 va = {0,0,0,0}, vc = {0,0,0,0};
        if (key0 >= 0) {
            const float* kk = kb + (size_t)key0 * EMBD;
            const float* vv = vb + (size_t)key0 * EMBD;
            ka = ld4(kk); kc = ld4(kk + 4);
            va = ld4(vv); vc = ld4(vv + 4);
        }
        for (int slot = w; slot < nun; slot += 16) {
            float4 nka = {0,0,0,0}, nkc = {0,0,0,0};
            float4 nva = {0,0,0,0}, nvc = {0,0,0,0};
            if (key1 >= 0) {
                const float* kk = kb + (size_t)key1 * EMBD;
                const float* vv = vb + (size_t)key1 * EMBD;
                nka = ld4(kk); nkc = ld4(kk + 4);
                nva = ld4(vv); nvc = ld4(vv + 4);
            }
            const int key2 = (slot + 32 < nun) ? klist[slot + 32] : -1;
            float sv = qa.x * ka.x + qa.y * ka.y + qa.z * ka.z + qa.w * ka.w
                     + qc.x * kc.x + qc.y * kc.y + qc.z * kc.z + qc.w * kc.w;
            sv += __shfl_xor(sv, 1, 8);
            sv += __shfl_xor(sv, 2, 8);
            sv += __shfl_xor(sv, 4, 8);
            const float p = __expf(sv * 0.125f);
            lsum += p;
            a0.x = fmaf(p, va.x, a0.x); a0.y = fmaf(p, va.y, a0.y);
            a0.z = fmaf(p, va.z, a0.z); a0.w = fmaf(p, va.w, a0.w);
            a1.x = fmaf(p, vc.x, a1.x); a1.y = fmaf(p, vc.y, a1.y);
            a1.z = fmaf(p, vc.z, a1.z); a1.w = fmaf(p, vc.w, a1.w);
            key0 = key1; ka = nka; kc = nkc; va = nva; vc = nvc; key1 = key2;
        }
    }
    if (sub == 0) redl[w][hq] = lsum;
    *reinterpret_cast<float4*>(&accb[w * ACP + lane * 8])     = a0;
    *reinterpret_cast<float4*>(&accb[w * ACP + lane * 8 + 4]) = a1;
    barrier_lgkm();

    if (t < EMBD) {
        const int h = t >> 6;
        float den = 0.f;
        #pragma unroll
        for (int ww = 0; ww < 16; ++ww) den += redl[ww][h];
        float s = 0.f;
        #pragma unroll
        for (int ww = 0; ww < 16; ++ww) s += accb[ww * ACP + t];
        merged[(size_t)b * EMBD + t] = s / den;
    }
}

__global__ __launch_bounds__(256) void proj_kernel_inplace(
    const float* __restrict__ merged,
    const float* __restrict__ Wo,
    float* __restrict__ out)
{
    const int b = blockIdx.x;
    const int t = threadIdx.x;
    __shared__ float mrow[EMBD];
    *reinterpret_cast<float2*>(&mrow[t * 2]) =
        *reinterpret_cast<const float2*>(&merged[(size_t)b * EMBD + t * 2]);
    __syncthreads();

    const float4* mv = reinterpret_cast<const float4*>(mrow);
    #pragma unroll
    for (int half = 0; half < 2; ++half) {
        const int j = t + half * 256;
        const float4* wrow = reinterpret_cast<const float4*>(Wo + (size_t)j * EMBD);
        float s = 0.f;
        #pragma unroll 4
        for (int i = 0; i < EMBD / 4; ++i) {
            const float4 wv = wrow[i];
            const float4 qv = mv[i];
            s += wv.x * qv.x + wv.y * qv.y + wv.z * qv.z + wv.w * qv.w;
        }
        out[(size_t)b * EMBD + j] = s;
    }
}

extern "C" void kernel_launch(void* const* d_in, const int* in_sizes, int n_in,
                              void* d_out, int out_size, void* d_ws, size_t ws_size,
                              hipStream_t stream) {
    const float* q    = (const float*)d_in[0];
    const float* kptr = (const float*)d_in[1];
    const float* vptr = (const float*)d_in[2];
    const float* Wo   = (const float*)d_in[3];
    const int*   mask = (const int*)d_in[4];
    float* out = (float*)d_out;

    const size_t need = (size_t)NB * CHUNKS * PREC * sizeof(float);  // 4.26MB
    if (ws_size >= need) {
        float* partials = (float*)d_ws;
        attn_chunk_kernel<<<NB * CHUNKS, 256, 0, stream>>>(q, kptr, vptr, mask, partials);
        merge_proj_kernel<<<NB, 256, 0, stream>>>(partials, Wo, out);
    } else {
        // fallback: R7 path, merged in d_out (in-place-safe proj)
        attn_kernel<<<NB, 1024, 0, stream>>>(q, kptr, vptr, mask, out);
        proj_kernel_inplace<<<NB, 256, 0, stream>>>(out, Wo, out);
    }
}

// Round 10
// 207.849 us; speedup vs baseline: 1.1012x; 1.1012x over previous
//
#include <hip/hip_runtime.h>

// MHA decode: B=256, NKEYS=2048, EMB=512, H=8, dh=64, f32.
// R9: R6 structure (two-pass, ballot-compacted mask-skip, no max-subtraction)
// but split each batch into 2 chunks of 1024 keys -> 512 blocks x 1024 thr,
// LDS padded to ~87KB so exactly ONE block per CU is resident (no stream
// fragmentation - R8's mistake); the HW dispatcher list-schedules 512 chunks
// over 256 CUs, halving the Binomial batch-size straggler tail. Chunks write
// raw partials (8 denoms + 512 acc); merge_proj sums 2 chunks, divides,
// projects with L2-tiled W_o.

#define NB    256
#define NK    2048
#define EMBD  512
#define NH    8
#define DH    64
#define CHUNKS 2
#define CKEYS  1024
#define SCP   2600   // score stride: 8KB-padded -> LDS 83.2KB forces 1 block/CU;
                     // bank(h*2600+k)=(8h+k)%32 -> worst 2-way on p-broadcast (free)
#define ACP   520
#define PREC  520    // partial record: [8 denom][512 acc]

__device__ __forceinline__ void barrier_lgkm() {
    asm volatile("s_waitcnt lgkmcnt(0)" ::: "memory");
    __builtin_amdgcn_s_barrier();
}

__device__ __forceinline__ float4 ld4(const float* p) {
    return *reinterpret_cast<const float4*>(p);
}

// 1024 threads = 16 waves; block = (batch b, chunk c of 1024 keys).
// Lane l owns floats [l*8,l*8+8) of each 2KB row -> head h = l>>3.
__global__ __launch_bounds__(1024) void attn_chunk_kernel(
    const float* __restrict__ q,
    const float* __restrict__ kptr,
    const float* __restrict__ vptr,
    const int* __restrict__ mask,
    float* __restrict__ partials)
{
    const int bid  = blockIdx.x;
    const int b    = bid >> 1;
    const int c    = bid & 1;
    const int t    = threadIdx.x;
    const int w    = t >> 6;        // wave 0..15
    const int lane = t & 63;
    const int hq   = lane >> 3;
    const int sub  = lane & 7;

    __shared__ float sc[NH][SCP];   // 83.2KB (indexed by GLOBAL key id)
    __shared__ int   klist[CKEYS];  // 4KB: compacted global key ids
    __shared__ int   wavecnt[16];
    __shared__ float redl[16][NH];

    const float* qb = q + (size_t)b * EMBD + lane * 8;
    const float4 qa = ld4(qb);
    const float4 qc = ld4(qb + 4);
    const float* kb = kptr + (size_t)b * NK * EMBD + lane * 8;
    const float* vb = vptr + (size_t)b * NK * EMBD + lane * 8;
    const int*   mrow = mask + (size_t)b * NK;

    // ---- ballot-compact this chunk's unmasked keys (wave w owns 64 keys) ----
    const int kG = c * CKEYS + w * 64 + lane;
    const int mk = mrow[kG];
    const unsigned long long bal = __ballot(mk == 0);
    if (lane == 0) wavecnt[w] = __popcll(bal);
    barrier_lgkm();
    int off = 0, nun = 0;
    #pragma unroll
    for (int i = 0; i < 16; ++i) {
        const int cc = wavecnt[i];
        off += (i < w) ? cc : 0;
        nun += cc;
    }
    const unsigned long long below = (1ull << lane) - 1ull;
    if (!mk) klist[off + __popcll(bal & below)] = kG;
    barrier_lgkm();

    // ---- K pass: 2-stage pipeline, p=exp(s/8), online per-head denom ----
    float lsum = 0.f;
    {
        int key0 = (w < nun) ? klist[w] : -1;
        int key1 = (w + 16 < nun) ? klist[w + 16] : -1;
        float4 ka = {0,0,0,0}, kc = {0,0,0,0};
        if (key0 >= 0) {
            const float* kk = kb + (size_t)key0 * EMBD;
            ka = ld4(kk); kc = ld4(kk + 4);
        }
        for (int slot = w; slot < nun; slot += 16) {
            float4 na = {0,0,0,0}, nc = {0,0,0,0};
            if (key1 >= 0) {
                const float* kk = kb + (size_t)key1 * EMBD;
                na = ld4(kk); nc = ld4(kk + 4);
            }
            const int key2 = (slot + 32 < nun) ? klist[slot + 32] : -1;
            float sv = qa.x * ka.x + qa.y * ka.y + qa.z * ka.z + qa.w * ka.w
                     + qc.x * kc.x + qc.y * kc.y + qc.z * kc.z + qc.w * kc.w;
            sv += __shfl_xor(sv, 1, 8);
            sv += __shfl_xor(sv, 2, 8);
            sv += __shfl_xor(sv, 4, 8);
            const float p = __expf(sv * 0.125f);  // no max-subtraction needed
            if (sub == 0) sc[hq][key0] = p;
            lsum += p;
            key0 = key1; ka = na; kc = nc; key1 = key2;
        }
    }
    if (sub == 0) redl[w][hq] = lsum;

    // V prologue before the barrier (lgkm-only keeps loads in flight)
    int vk0 = (w < nun) ? klist[w] : -1;
    int vk1 = (w + 16 < nun) ? klist[w + 16] : -1;
    float4 va = {0,0,0,0}, vc = {0,0,0,0};
    if (vk0 >= 0) {
        const float* vv = vb + (size_t)vk0 * EMBD;
        va = ld4(vv); vc = ld4(vv + 4);
    }
    barrier_lgkm();   // p values + denoms visible

    // ---- V pass: 2-stage pipeline ----
    float4 a0 = {0.f, 0.f, 0.f, 0.f};
    float4 a1 = {0.f, 0.f, 0.f, 0.f};
    for (int slot = w; slot < nun; slot += 16) {
        float4 nva = {0,0,0,0}, nvc = {0,0,0,0};
        if (vk1 >= 0) {
            const float* vv = vb + (size_t)vk1 * EMBD;
            nva = ld4(vv); nvc = ld4(vv + 4);
        }
        const int vk2 = (slot + 32 < nun) ? klist[slot + 32] : -1;
        const float p = sc[hq][vk0];
        a0.x = fmaf(p, va.x, a0.x); a0.y = fmaf(p, va.y, a0.y);
        a0.z = fmaf(p, va.z, a0.z); a0.w = fmaf(p, va.w, a0.w);
        a1.x = fmaf(p, vc.x, a1.x); a1.y = fmaf(p, vc.y, a1.y);
        a1.z = fmaf(p, vc.z, a1.z); a1.w = fmaf(p, vc.w, a1.w);
        vk0 = vk1; va = nva; vc = nvc; vk1 = vk2;
    }

    barrier_lgkm();   // all sc reads done -> reuse as acc buffer
    float* accb = &sc[0][0];
    *reinterpret_cast<float4*>(&accb[w * ACP + lane * 8])     = a0;
    *reinterpret_cast<float4*>(&accb[w * ACP + lane * 8 + 4]) = a1;
    barrier_lgkm();

    // ---- write raw partial record (undivided) ----
    float* rec = partials + (size_t)bid * PREC;
    if (t < NH) {
        float d = 0.f;
        #pragma unroll
        for (int ww = 0; ww < 16; ++ww) d += redl[ww][t];
        rec[t] = d;
    }
    if (t < EMBD) {
        float s = 0.f;
        #pragma unroll
        for (int ww = 0; ww < 16; ++ww) s += accb[ww * ACP + t];
        rec[8 + t] = s;
    }
}

// Merge 2 chunk-partials per batch, divide by global denom, then project.
// Block = 8 batches x 64 j's (W_o tile stays L2-resident).
__global__ __launch_bounds__(256) void merge_proj_kernel(
    const float* __restrict__ partials,
    const float* __restrict__ Wo,
    float* __restrict__ out)
{
    const int bt = blockIdx.x >> 3;   // batch tile (8 batches)
    const int jt = blockIdx.x & 7;    // j tile (64 outputs)
    const int t  = threadIdx.x;
    __shared__ float mrow[8][EMBD];   // 16KB merged rows
    __shared__ float sden[64];

    if (t < 64) {
        const int bb = t >> 3, h = t & 7;
        const float* base = partials + (size_t)((bt * 8 + bb) * CHUNKS) * PREC;
        float d = 0.f;
        #pragma unroll
        for (int cc = 0; cc < CHUNKS; ++cc) d += base[cc * PREC + h];
        sden[t] = d;
    }
    #pragma unroll
    for (int e = 0; e < 16; ++e) {
        const int idx = e * 256 + t;
        const int bb = idx >> 9, el = idx & 511;
        const float* base = partials + (size_t)((bt * 8 + bb) * CHUNKS) * PREC + 8 + el;
        float s = 0.f;
        #pragma unroll
        for (int cc = 0; cc < CHUNKS; ++cc) s += base[cc * PREC];
        mrow[bb][el] = s;
    }
    __syncthreads();
    #pragma unroll
    for (int e = 0; e < 16; ++e) {
        const int idx = e * 256 + t;
        const int bb = idx >> 9, el = idx & 511;
        mrow[bb][el] /= sden[bb * 8 + (el >> 6)];
    }
    __syncthreads();

    const int j    = jt * 64 + (t & 63);
    const int brel = t >> 6;
    const float4* wrow = reinterpret_cast<const float4*>(Wo + (size_t)j * EMBD);
    const float4* m0 = reinterpret_cast<const float4*>(&mrow[brel][0]);
    const float4* m1 = reinterpret_cast<const float4*>(&mrow[brel + 4][0]);
    float s0 = 0.f, s1 = 0.f;
    #pragma unroll 4
    for (int i = 0; i < 128; ++i) {
        const float4 wv = wrow[i];
        const float4 x0 = m0[i];
        const float4 x1 = m1[i];
        s0 += wv.x * x0.x + wv.y * x0.y + wv.z * x0.z + wv.w * x0.w;
        s1 += wv.x * x1.x + wv.y * x1.y + wv.z * x1.z + wv.w * x1.w;
    }
    out[(size_t)(bt * 8 + brel) * EMBD + j] = s0;
    out[(size_t)(bt * 8 + brel + 4) * EMBD + j] = s1;
}

// ---------------- fallback path (small ws): R6 full-batch ----------------
__global__ __launch_bounds__(1024) void attn_kernel(
    const float* __restrict__ q,
    const float* __restrict__ kptr,
    const float* __restrict__ vptr,
    const int* __restrict__ mask,
    float* __restrict__ merged)
{
    const int b    = blockIdx.x;
    const int t    = threadIdx.x;
    const int w    = t >> 6;
    const int lane = t & 63;
    const int hq   = lane >> 3;
    const int sub  = lane & 7;

    __shared__ float sc[NH][2052];
    __shared__ int   klist[NK];
    __shared__ int   wavecnt[16];
    __shared__ float redl[16][NH];

    const float* qb = q + (size_t)b * EMBD + lane * 8;
    const float4 qa = ld4(qb);
    const float4 qc = ld4(qb + 4);
    const float* kb = kptr + (size_t)b * NK * EMBD + lane * 8;
    const float* vb = vptr + (size_t)b * NK * EMBD + lane * 8;
    const int*   mrow = mask + (size_t)b * NK;

    const int kA = w * 128 + lane;
    const int kB = kA + 64;
    const int mA = mrow[kA];
    const int mB = mrow[kB];
    const unsigned long long balA = __ballot(mA == 0);
    const unsigned long long balB = __ballot(mB == 0);
    if (lane == 0) wavecnt[w] = __popcll(balA) + __popcll(balB);
    barrier_lgkm();

    int off = 0, nun = 0;
    #pragma unroll
    for (int i = 0; i < 16; ++i) {
        const int cv = wavecnt[i];
        off += (i < w) ? cv : 0;
        nun += cv;
    }
    const unsigned long long below = (1ull << lane) - 1ull;
    if (!mA) klist[off + __popcll(balA & below)] = kA;
    if (!mB) klist[off + __popcll(balA) + __popcll(balB & below)] = kB;
    barrier_lgkm();

    float lsum = 0.f;
    {
        int key0 = (w < nun) ? klist[w] : -1;
        int key1 = (w + 16 < nun) ? klist[w + 16] : -1;
        float4 ka = {0,0,0,0}, kc = {0,0,0,0};
        if (key0 >= 0) {
            const float* kk = kb + (size_t)key0 * EMBD;
            ka = ld4(kk); kc = ld4(kk + 4);
        }
        for (int slot = w; slot < nun; slot += 16) {
            float4 na = {0,0,0,0}, nc = {0,0,0,0};
            if (key1 >= 0) {
                const float* kk = kb + (size_t)key1 * EMBD;
                na = ld4(kk); nc = ld4(kk + 4);
            }
            const int key2 = (slot + 32 < nun) ? klist[slot + 32] : -1;
            float sv = qa.x * ka.x + qa.y * ka.y + qa.z * ka.z + qa.w * ka.w
                     + qc.x * kc.x + qc.y * kc.y + qc.z * kc.z + qc.w * kc.w;
            sv += __shfl_xor(sv, 1, 8);
            sv += __shfl_xor(sv, 2, 8);
            sv += __shfl_xor(sv, 4, 8);
            const float p = __expf(sv * 0.125f);
            if (sub == 0) sc[hq][key0] = p;
            lsum += p;
            key0 = key1; ka = na; kc = nc; key1 = key2;
        }
    }
    if (sub == 0) redl[w][hq] = lsum;

    int vk0 = (w < nun) ? klist[w] : -1;
    int vk1 = (w + 16 < nun) ? klist[w + 16] : -1;
    float4 va = {0,0,0,0}, vc = {0,0,0,0};
    if (vk0 >= 0) {
        const float* vv = vb + (size_t)vk0 * EMBD;
        va = ld4(vv); vc = ld4(vv + 4);
    }
    barrier_lgkm();

    float4 a0 = {0.f, 0.f, 0.f, 0.f};
    float4 a1 = {0.f, 0.f, 0.f, 0.f};
    for (int slot = w; slot < nun; slot += 16) {
        float4 nva = {0,0,0,0}, nvc = {0,0,0,0};
        if (vk1 >= 0) {
            const float* vv = vb + (size_t)vk1 * EMBD;
            nva = ld4(vv); nvc = ld4(vv + 4);
        }
        const int vk2 = (slot + 32 < nun) ? klist[slot + 32] : -1;
        const float p = sc[hq][vk0];
        a0.x = fmaf(p, va.x, a0.x); a0.y = fmaf(p, va.y, a0.y);
        a0.z = fmaf(p, va.z, a0.z); a0.w = fmaf(p, va.w, a0.w);
        a1.x = fmaf(p, vc.x, a1.x); a1.y = fmaf(p, vc.y, a1.y);
        a1.z = fmaf(p, vc.z, a1.z); a1.w = fmaf(p, vc.w, a1.w);
        vk0 = vk1; va = nva; vc = nvc; vk1 = vk2;
    }

    barrier_lgkm();
    float* accb = &sc[0][0];
    *reinterpret_cast<float4*>(&accb[w * ACP + lane * 8])     = a0;
    *reinterpret_cast<float4*>(&accb[w * ACP + lane * 8 + 4]) = a1;
    barrier_lgkm();

    if (t < EMBD) {
        const int h = t >> 6;
        float den = 0.f;
        #pragma unroll
        for (int ww = 0; ww < 16; ++ww) den += redl[ww][h];
        float s = 0.f;
        #pragma unroll
        for (int ww = 0; ww < 16; ++ww) s += accb[ww * ACP + t];
        merged[(size_t)b * EMBD + t] = s / den;
    }
}

__global__ __launch_bounds__(256) void proj_kernel_inplace(
    const float* __restrict__ merged,
    const float* __restrict__ Wo,
    float* __restrict__ out)
{
    const int b = blockIdx.x;
    const int t = threadIdx.x;
    __shared__ float mrow[EMBD];
    *reinterpret_cast<float2*>(&mrow[t * 2]) =
        *reinterpret_cast<const float2*>(&merged[(size_t)b * EMBD + t * 2]);
    __syncthreads();

    const float4* mv = reinterpret_cast<const float4*>(mrow);
    #pragma unroll
    for (int half = 0; half < 2; ++half) {
        const int j = t + half * 256;
        const float4* wrow = reinterpret_cast<const float4*>(Wo + (size_t)j * EMBD);
        float s = 0.f;
        #pragma unroll 4
        for (int i = 0; i < EMBD / 4; ++i) {
            const float4 wv = wrow[i];
            const float4 qv = mv[i];
            s += wv.x * qv.x + wv.y * qv.y + wv.z * qv.z + wv.w * qv.w;
        }
        out[(size_t)b * EMBD + j] = s;
    }
}

extern "C" void kernel_launch(void* const* d_in, const int* in_sizes, int n_in,
                              void* d_out, int out_size, void* d_ws, size_t ws_size,
                              hipStream_t stream) {
    const float* q    = (const float*)d_in[0];
    const float* kptr = (const float*)d_in[1];
    const float* vptr = (const float*)d_in[2];
    const float* Wo   = (const float*)d_in[3];
    const int*   mask = (const int*)d_in[4];
    float* out = (float*)d_out;

    const size_t need = (size_t)NB * CHUNKS * PREC * sizeof(float);  // 1.06MB
    if (ws_size >= need) {
        float* partials = (float*)d_ws;
        attn_chunk_kernel<<<NB * CHUNKS, 1024, 0, stream>>>(q, kptr, vptr, mask, partials);
        merge_proj_kernel<<<NB, 256, 0, stream>>>(partials, Wo, out);
    } else {
        attn_kernel<<<NB, 1024, 0, stream>>>(q, kptr, vptr, mask, out);
        proj_kernel_inplace<<<NB, 256, 0, stream>>>(out, Wo, out);
    }
}